// Round 14
// baseline (506.610 us; speedup 1.0000x reference)
//
#include <hip/hip_runtime.h>

namespace {

constexpr int SEQ = 2048, BATCH = 1024, IN = 10, H = 20;
constexpr int XS  = 32;                  // x steps per LDS chunk
constexpr int XRW = 16;                  // ints per step-row: chain0 pairs @0..4, chain1 @8..12
constexpr float L2E = 1.4426950408889634f;
constexpr float K2  = -2.0f * L2E;       // carried scale on c:  c' = K2 * c

typedef _Float16 h2t __attribute__((ext_vector_type(2)));

__device__ __forceinline__ float rcpf(float x) { return __builtin_amdgcn_rcpf(x); }
__device__ __forceinline__ float xp2(float x)  { return __builtin_amdgcn_exp2f(x); }

__device__ __forceinline__ int pk(float a, float b) {
    auto v = __builtin_amdgcn_cvt_pkrtz(a, b);
    int i; __builtin_memcpy(&i, &v, 4); return i;
}
__device__ __forceinline__ float dot2(int a, int b, float c) {
    h2t ha, hb; __builtin_memcpy(&ha, &a, 4); __builtin_memcpy(&hb, &b, 4);
    return __builtin_amdgcn_fdot2(ha, hb, c, false);
}
// lane^1 (quad_perm [1,0,3,2] = 0xB1)
__device__ __forceinline__ float dpp_x1(float v) {
    int i; __builtin_memcpy(&i, &v, 4);
    int r = __builtin_amdgcn_update_dpp(0, i, 0xB1, 0xF, 0xF, true);
    float f; __builtin_memcpy(&f, &r, 4); return f;
}

template<int DIR>
__device__ __forceinline__ void run_dir(const float* __restrict__ x,
                                        const float* __restrict__ h0,
                                        const float* __restrict__ c0,
                                        const float* __restrict__ w_ih,
                                        const float* __restrict__ w_hh,
                                        const float* __restrict__ bi,
                                        const float* __restrict__ bh,
                                        float* __restrict__ out,
                                        float* __restrict__ h_n,
                                        float* __restrict__ c_n,
                                        int b2, int lane,
                                        int* xlds, int* hl)
{
    // lane = 20c + u : chain c (0/1), unit u. Lanes 40..63 idle (mirror chain 1).
    const int  c    = lane / 20;
    const int  u    = lane % 20;
    const int  cc   = (c < 2) ? c : 1;
    const bool act  = (c < 2);
    const int  bgl  = 2 * b2 + cc;

    // h publish: even-u active lanes hold pair (h_u, h_{u+1}) after dpp_x1.
    // ALL lanes store every step (dump slots otherwise) -> stops LLVM from
    // CSE-hoisting the hl loads across steps (R9/R10 lesson).
    const bool okp  = act && ((u & 1) == 0);
    const int  offH = okp ? (cc * 16 + (u >> 1)) : (32 + lane);

    // ---- per-lane weights: all 4 gates of unit u, fp16-packed, pre-scaled ----
    // q=0(i),1(f),3(o): scale -L2E  ->  t=exp2(a)=e^{-preact}
    // q=2(g~):          scale K2    ->  t=exp2(a)=e^{-2 preact}
    int wh[4][10], wi[4][5]; float bias[4];
    #pragma unroll
    for (int q = 0; q < 4; ++q) {
        const float sc = (q == 2) ? K2 : (-L2E);
        const int g = q * H + u;
        #pragma unroll
        for (int k = 0; k < 10; ++k)
            wh[q][k] = pk(w_hh[g * H + 2 * k] * sc, w_hh[g * H + 2 * k + 1] * sc);
        #pragma unroll
        for (int k = 0; k < 5; ++k)
            wi[q][k] = pk(w_ih[g * IN + 2 * k] * sc, w_ih[g * IN + 2 * k + 1] * sc);
        bias[q] = (bi[g] + bh[g]) * sc;
    }

    float cv = c0[(DIR * BATCH + bgl) * H + u] * K2;   // carried pre-scaled
    float hv = h0[(DIR * BATCH + bgl) * H + u];

    // ---- x chunk staging ----
    constexpr ptrdiff_t XSTEP = DIR ? -(ptrdiff_t)(BATCH * IN) : (ptrdiff_t)(BATCH * IN);
    constexpr ptrdiff_t XOFF0 = DIR ? (ptrdiff_t)(SEQ - 1) * (BATCH * IN) : 0;
    const float* xbase = x + (2 * b2) * IN + XOFF0;

    float2 pend[5];
    auto issue_chunk = [&](int s0) {
        #pragma unroll
        for (int i = 0; i < 5; ++i) {
            const int e = lane + 64 * i;               // 0..319
            pend[i] = *(const float2*)(xbase + (ptrdiff_t)(s0 + e / 10) * XSTEP + 2 * (e % 10));
        }
    };
    auto write_chunk = [&](int buf) {
        #pragma unroll
        for (int i = 0; i < 5; ++i) {
            const int e = lane + 64 * i;
            const int j = e % 10;
            xlds[buf * (XS * XRW) + (e / 10) * XRW + j + (j >= 5 ? 3 : 0)] = pk(pend[i].x, pend[i].y);
        }
    };
    auto read_x = [&](const int* xr, int (&xq)[5]) {
        const int4 xa = *(const int4*)xr;
        xq[0] = xa.x; xq[1] = xa.y; xq[2] = xa.z; xq[3] = xa.w; xq[4] = xr[4];
    };

    int hp[10];
    auto read_h = [&]() {
        const int* hr = &hl[cc * 16];
        const int4 hA = *(const int4*)hr;
        const int4 hB = *(const int4*)(hr + 4);
        const int2 hC = *(const int2*)(hr + 8);
        hp[0]=hA.x; hp[1]=hA.y; hp[2]=hA.z; hp[3]=hA.w;
        hp[4]=hB.x; hp[5]=hB.y; hp[6]=hB.z; hp[7]=hB.w;
        hp[8]=hC.x; hp[9]=hC.y;
    };

    issue_chunk(0);  write_chunk(0);
    issue_chunk(XS);

    hl[offH] = pk(hv, dpp_x1(hv));                     // initial publish (full exec)
    read_h();

    // ---- out addressing: uniform row offset (SALU) + constant lane offset ----
    constexpr ptrdiff_t OSTEP = DIR ? -(ptrdiff_t)(BATCH * 2 * H) : (ptrdiff_t)(BATCH * 2 * H);
    ptrdiff_t           orow  = DIR ? (ptrdiff_t)(SEQ - 1) * (BATCH * 2 * H) : 0;
    const int           ocst  = bgl * (2 * H) + DIR * H + u;

    // one LSTM step from packed x row; merged-rcp nonlinearity (7 trans total)
    auto STEP = [&](const int (&xq)[5]) {
        float a0 = bias[0], a1 = bias[1], a2 = bias[2], a3 = bias[3];
        #pragma unroll
        for (int k = 0; k < 5; ++k) {
            a0 = dot2(xq[k], wi[0][k], a0);
            a1 = dot2(xq[k], wi[1][k], a1);
            a2 = dot2(xq[k], wi[2][k], a2);
            a3 = dot2(xq[k], wi[3][k], a3);
        }
        #pragma unroll
        for (int k = 0; k < 10; ++k) {
            a0 = dot2(hp[k], wh[0][k], a0);
            a1 = dot2(hp[k], wh[1][k], a1);
            a2 = dot2(hp[k], wh[2][k], a2);
            a3 = dot2(hp[k], wh[3][k], a3);
        }

        // t_i=e^{-i}, t_f=e^{-f}, t_g=e^{-2g~}, t_o=e^{-o}
        const float ti = xp2(a0), tf = xp2(a1), tg = xp2(a2), to = xp2(a3);
        const float Pi = 1.0f + ti, Pf = 1.0f + tf, Pg = 1.0f + tg, Po = 1.0f + to;
        const float Mg  = fmaf(-K2, tg, K2);           // K2*(1-t_g)
        const float pig = Pi * Pg;
        const float num = fmaf(Mg, Pf, cv * pig);      // cv*Pi*Pg + K2(1-tg)*Pf
        cv = num * rcpf(Pf * pig);                     // one rcp for the whole c-update

        const float tc = xp2(cv);                      // e^{-2c}  (cv = K2*c)
        const float Pc = 1.0f + tc;
        hv = (1.0f - tc) * rcpf(Po * Pc);              // sig(o)*tanh(c), one rcp

        hl[offH] = pk(hv, dpp_x1(hv));                 // full-exec pk/dpp, uncond store
        read_h();                                      // in-order DS: next step's h

        if (act) __builtin_nontemporal_store(hv, out + orow + ocst);
        orow += OSTEP;
    };

    int xqA[5], xqB[5];
    {
        const int* b0p = &xlds[0] + cc * 8;
        read_x(b0p, xqA);                              // prime row 0
    }

    for (int s0 = 0; s0 < SEQ; s0 += XS) {
        const int  buf  = (s0 >> 5) & 1;
        const int* bptr = &xlds[buf * (XS * XRW)] + cc * 8;
        #pragma unroll 2
        for (int ss = 0; ss < XS; ss += 2) {
            read_x(bptr + (ss + 1) * XRW, xqB);        // prefetch row ss+1
            STEP(xqA);
            read_x(bptr + (((ss + 2) & 31) * XRW), xqA); // prefetch ss+2 (wraps: garbage, re-primed)
            STEP(xqB);
        }
        // ---- chunk boundary: publish pending chunk, prefetch next-next, prime row 0 ----
        if (s0 + XS < SEQ) {
            write_chunk(buf ^ 1);                      // counted-vmcnt wait on old loads only
            if (s0 + 2 * XS < SEQ) issue_chunk(s0 + 2 * XS);
            read_x(&xlds[(buf ^ 1) * (XS * XRW)] + cc * 8, xqA);
        }
    }

    if (act) {
        h_n[(DIR * BATCH + bgl) * H + u] = hv;
        c_n[(DIR * BATCH + bgl) * H + u] = cv * (1.0f / K2);
    }
}

__launch_bounds__(64)
__global__ void lstm_bidir(const float* __restrict__ x,
                           const float* __restrict__ h0,
                           const float* __restrict__ c0,
                           const float* __restrict__ w_ih_f, const float* __restrict__ w_hh_f,
                           const float* __restrict__ b_ih_f, const float* __restrict__ b_hh_f,
                           const float* __restrict__ w_ih_b, const float* __restrict__ w_hh_b,
                           const float* __restrict__ b_ih_b, const float* __restrict__ b_hh_b,
                           float* __restrict__ out, float* __restrict__ h_n, float* __restrict__ c_n)
{
    __shared__ __align__(16) int xlds[2 * XS * XRW];   // x chunks, fp16-pair packed (4 KiB)
    __shared__ __align__(16) int hl[96];               // h pairs c0:[0..9] c1:[16..25] + dumps

    const int b2   = blockIdx.x;
    const int lane = threadIdx.x;

    if (blockIdx.y == 0)
        run_dir<0>(x, h0, c0, w_ih_f, w_hh_f, b_ih_f, b_hh_f, out, h_n, c_n, b2, lane, xlds, hl);
    else
        run_dir<1>(x, h0, c0, w_ih_b, w_hh_b, b_ih_b, b_hh_b, out, h_n, c_n, b2, lane, xlds, hl);
}

} // namespace

extern "C" void kernel_launch(void* const* d_in, const int* in_sizes, int n_in,
                              void* d_out, int out_size, void* d_ws, size_t ws_size,
                              hipStream_t stream)
{
    const float* x      = (const float*)d_in[0];
    const float* h0     = (const float*)d_in[1];
    const float* c0     = (const float*)d_in[2];
    const float* w_ih_f = (const float*)d_in[3];
    const float* w_hh_f = (const float*)d_in[4];
    const float* b_ih_f = (const float*)d_in[5];
    const float* b_hh_f = (const float*)d_in[6];
    const float* w_ih_b = (const float*)d_in[7];
    const float* w_hh_b = (const float*)d_in[8];
    const float* b_ih_b = (const float*)d_in[9];
    const float* b_hh_b = (const float*)d_in[10];

    float* out = (float*)d_out;
    float* h_n = out + (size_t)SEQ * BATCH * 2 * H;
    float* c_n = h_n + (size_t)2 * BATCH * H;

    dim3 grid(BATCH / 2, 2), block(64);
    hipLaunchKernelGGL(lstm_bidir, grid, block, 0, stream,
                       x, h0, c0, w_ih_f, w_hh_f, b_ih_f, b_hh_f,
                       w_ih_b, w_hh_b, b_ih_b, b_hh_b, out, h_n, c_n);
}

// Round 15
// 491.674 us; speedup vs baseline: 1.0304x; 1.0304x over previous
//
#include <hip/hip_runtime.h>

namespace {

constexpr int SEQ = 2048, BATCH = 1024, IN = 10, H = 20;
constexpr int XS  = 32;                  // x steps per LDS chunk
constexpr int XRW = 16;                  // ints per step-row: chain0 pairs @0..4, chain1 @8..12
constexpr float L2E = 1.4426950408889634f;
constexpr float K2  = -2.0f * L2E;       // carried scale on c:  c' = K2 * c

typedef _Float16 h2t __attribute__((ext_vector_type(2)));

__device__ __forceinline__ float rcpf(float x) { return __builtin_amdgcn_rcpf(x); }
__device__ __forceinline__ float xp2(float x)  { return __builtin_amdgcn_exp2f(x); }

__device__ __forceinline__ int pk(float a, float b) {
    auto v = __builtin_amdgcn_cvt_pkrtz(a, b);
    int i; __builtin_memcpy(&i, &v, 4); return i;
}
__device__ __forceinline__ float dot2(int a, int b, float c) {
    h2t ha, hb; __builtin_memcpy(&ha, &a, 4); __builtin_memcpy(&hb, &b, 4);
    return __builtin_amdgcn_fdot2(ha, hb, c, false);
}
// lane^1 (quad_perm [1,0,3,2] = 0xB1)
__device__ __forceinline__ float dpp_x1(float v) {
    int i; __builtin_memcpy(&i, &v, 4);
    int r = __builtin_amdgcn_update_dpp(0, i, 0xB1, 0xF, 0xF, true);
    float f; __builtin_memcpy(&f, &r, 4); return f;
}

struct XRow { int4 a; int b; };

template<int DIR>
__device__ __forceinline__ void run_dir(const float* __restrict__ x,
                                        const float* __restrict__ h0,
                                        const float* __restrict__ c0,
                                        const float* __restrict__ w_ih,
                                        const float* __restrict__ w_hh,
                                        const float* __restrict__ bi,
                                        const float* __restrict__ bh,
                                        float* __restrict__ out,
                                        float* __restrict__ h_n,
                                        float* __restrict__ c_n,
                                        int b2, int lane,
                                        int* xlds, int* hl)
{
    // lane = 20c + u : chain c (0/1), unit u. Lanes 40..63 idle (mirror chain 1).
    const int  c    = lane / 20;
    const int  u    = lane % 20;
    const int  cc   = (c < 2) ? c : 1;
    const bool act  = (c < 2);
    const int  bgl  = 2 * b2 + cc;

    // h publish: even-u active lanes hold pair (h_u, h_{u+1}) after dpp_x1.
    // ALL lanes store every step (dump slots otherwise) -> stops LLVM from
    // CSE-hoisting the hl loads across steps (R9/R10 lesson).
    const bool okp  = act && ((u & 1) == 0);
    const int  offH = okp ? (cc * 16 + (u >> 1)) : (32 + lane);

    // ---- per-lane weights: all 4 gates of unit u, fp16-packed, pre-scaled ----
    int wh[4][10], wi[4][5]; float bias[4];
    #pragma unroll
    for (int q = 0; q < 4; ++q) {
        const float sc = (q == 2) ? K2 : (-L2E);
        const int g = q * H + u;
        #pragma unroll
        for (int k = 0; k < 10; ++k)
            wh[q][k] = pk(w_hh[g * H + 2 * k] * sc, w_hh[g * H + 2 * k + 1] * sc);
        #pragma unroll
        for (int k = 0; k < 5; ++k)
            wi[q][k] = pk(w_ih[g * IN + 2 * k] * sc, w_ih[g * IN + 2 * k + 1] * sc);
        bias[q] = (bi[g] + bh[g]) * sc;
    }

    float cv = c0[(DIR * BATCH + bgl) * H + u] * K2;   // carried pre-scaled
    float hv = h0[(DIR * BATCH + bgl) * H + u];

    // ---- x chunk staging ----
    constexpr ptrdiff_t XSTEP = DIR ? -(ptrdiff_t)(BATCH * IN) : (ptrdiff_t)(BATCH * IN);
    constexpr ptrdiff_t XOFF0 = DIR ? (ptrdiff_t)(SEQ - 1) * (BATCH * IN) : 0;
    const float* xbase = x + (2 * b2) * IN + XOFF0;

    float2 pend[5];
    auto issue_chunk = [&](int s0) {
        #pragma unroll
        for (int i = 0; i < 5; ++i) {
            const int e = lane + 64 * i;               // 0..319
            pend[i] = *(const float2*)(xbase + (ptrdiff_t)(s0 + e / 10) * XSTEP + 2 * (e % 10));
        }
    };
    auto write_chunk = [&](int buf) {
        #pragma unroll
        for (int i = 0; i < 5; ++i) {
            const int e = lane + 64 * i;
            const int j = e % 10;
            xlds[buf * (XS * XRW) + (e / 10) * XRW + j + (j >= 5 ? 3 : 0)] = pk(pend[i].x, pend[i].y);
        }
    };
    auto read_x = [&](const int* bptr, int ss) -> XRow {
        const int* xr = bptr + ss * XRW;
        XRow r; r.a = *(const int4*)xr; r.b = xr[4]; return r;
    };

    int4 hA, hB; int2 hC;
    auto read_h = [&]() {
        const int* hr = &hl[cc * 16];
        hA = *(const int4*)hr;
        hB = *(const int4*)(hr + 4);
        hC = *(const int2*)(hr + 8);
    };

    issue_chunk(0);  write_chunk(0);
    issue_chunk(XS);

    hl[offH] = pk(hv, dpp_x1(hv));                     // initial publish (full exec)
    read_h();

    // ---- out addressing: uniform row offset (SALU) + constant lane offset ----
    constexpr ptrdiff_t OSTEP = DIR ? -(ptrdiff_t)(BATCH * 2 * H) : (ptrdiff_t)(BATCH * 2 * H);
    ptrdiff_t           orow  = DIR ? (ptrdiff_t)(SEQ - 1) * (BATCH * 2 * H) : 0;
    const int           ocst  = bgl * (2 * H) + DIR * H + u;

    // pipelined accumulators: PRE_X fills a0..a3 with bias + x-dots (independent of h),
    // issued in the tail shadow of the previous step; STEP_H finishes the step.
    float a0, a1, a2, a3;
    auto PRE_X = [&](const XRow& xr) {
        const int xq[5] = { xr.a.x, xr.a.y, xr.a.z, xr.a.w, xr.b };
        a0 = bias[0]; a1 = bias[1]; a2 = bias[2]; a3 = bias[3];
        #pragma unroll
        for (int k = 0; k < 5; ++k) {
            a0 = dot2(xq[k], wi[0][k], a0);
            a1 = dot2(xq[k], wi[1][k], a1);
            a2 = dot2(xq[k], wi[2][k], a2);
            a3 = dot2(xq[k], wi[3][k], a3);
        }
    };
    auto STEP_H = [&]() {
        const int hp[10] = { hA.x, hA.y, hA.z, hA.w, hB.x, hB.y, hB.z, hB.w, hC.x, hC.y };
        #pragma unroll
        for (int k = 0; k < 10; ++k) {
            a0 = dot2(hp[k], wh[0][k], a0);
            a1 = dot2(hp[k], wh[1][k], a1);
            a2 = dot2(hp[k], wh[2][k], a2);
            a3 = dot2(hp[k], wh[3][k], a3);
        }

        // t_i=e^{-i}, t_f=e^{-f}, t_g=e^{-2g~}, t_o=e^{-o}; merged rcps (7 trans total)
        const float ti = xp2(a0), tf = xp2(a1), tg = xp2(a2), to = xp2(a3);
        const float Pi = 1.0f + ti, Pf = 1.0f + tf, Pg = 1.0f + tg, Po = 1.0f + to;
        const float Mg  = fmaf(-K2, tg, K2);           // K2*(1-t_g)
        const float pig = Pi * Pg;
        const float num = fmaf(Mg, Pf, cv * pig);      // cv*Pi*Pg + K2(1-tg)*Pf
        cv = num * rcpf(Pf * pig);

        const float tc = xp2(cv);                      // e^{-2c}  (cv = K2*c)
        const float Pc = 1.0f + tc;
        hv = (1.0f - tc) * rcpf(Po * Pc);              // sig(o)*tanh(c)

        hl[offH] = pk(hv, dpp_x1(hv));                 // full-exec pk/dpp, uncond store
        read_h();                                      // in-order DS: next step's h

        if (act) __builtin_nontemporal_store(hv, out + orow + ocst);
        orow += OSTEP;
    };

    // prime: row 0 of chunk 0
    XRow xq0 = read_x(&xlds[0] + cc * 8, 0), xq1;
    PRE_X(xq0);

    for (int s0 = 0; s0 < SEQ; s0 += XS) {
        const int  buf  = (s0 >> 5) & 1;
        const int* bptr = &xlds[buf * (XS * XRW)] + cc * 8;

        // steps ss..ss+1 per iteration, ss = 0..28 (30 steps)
        #pragma unroll 3
        for (int ss = 0; ss < XS - 2; ss += 2) {
            xq1 = read_x(bptr, ss + 1);
            STEP_H();                                  // finish step ss
            PRE_X(xq1);                                // x-dots for ss+1 fill the tail
            xq0 = read_x(bptr, ss + 2);
            STEP_H();                                  // finish step ss+1
            PRE_X(xq0);                                // x-dots for ss+2
        }
        // peeled steps 30, 31 with chunk-boundary work in step 31's shadow
        xq1 = read_x(bptr, XS - 1);
        STEP_H();                                      // step 30
        PRE_X(xq1);
        const bool more = (s0 + XS < SEQ);
        if (more) {
            write_chunk(buf ^ 1);                      // counted-vmcnt wait on old loads only
            if (s0 + 2 * XS < SEQ) issue_chunk(s0 + 2 * XS);
        }
        STEP_H();                                      // step 31
        if (more) {
            xq0 = read_x(&xlds[(buf ^ 1) * (XS * XRW)] + cc * 8, 0);
            PRE_X(xq0);
        }
    }

    if (act) {
        h_n[(DIR * BATCH + bgl) * H + u] = hv;
        c_n[(DIR * BATCH + bgl) * H + u] = cv * (1.0f / K2);
    }
}

__launch_bounds__(64)
__global__ void lstm_bidir(const float* __restrict__ x,
                           const float* __restrict__ h0,
                           const float* __restrict__ c0,
                           const float* __restrict__ w_ih_f, const float* __restrict__ w_hh_f,
                           const float* __restrict__ b_ih_f, const float* __restrict__ b_hh_f,
                           const float* __restrict__ w_ih_b, const float* __restrict__ w_hh_b,
                           const float* __restrict__ b_ih_b, const float* __restrict__ b_hh_b,
                           float* __restrict__ out, float* __restrict__ h_n, float* __restrict__ c_n)
{
    __shared__ __align__(16) int xlds[2 * XS * XRW];   // x chunks, fp16-pair packed (4 KiB)
    __shared__ __align__(16) int hl[96];               // h pairs c0:[0..9] c1:[16..25] + dumps

    const int b2   = blockIdx.x;
    const int lane = threadIdx.x;

    if (blockIdx.y == 0)
        run_dir<0>(x, h0, c0, w_ih_f, w_hh_f, b_ih_f, b_hh_f, out, h_n, c_n, b2, lane, xlds, hl);
    else
        run_dir<1>(x, h0, c0, w_ih_b, w_hh_b, b_ih_b, b_hh_b, out, h_n, c_n, b2, lane, xlds, hl);
}

} // namespace

extern "C" void kernel_launch(void* const* d_in, const int* in_sizes, int n_in,
                              void* d_out, int out_size, void* d_ws, size_t ws_size,
                              hipStream_t stream)
{
    const float* x      = (const float*)d_in[0];
    const float* h0     = (const float*)d_in[1];
    const float* c0     = (const float*)d_in[2];
    const float* w_ih_f = (const float*)d_in[3];
    const float* w_hh_f = (const float*)d_in[4];
    const float* b_ih_f = (const float*)d_in[5];
    const float* b_hh_f = (const float*)d_in[6];
    const float* w_ih_b = (const float*)d_in[7];
    const float* w_hh_b = (const float*)d_in[8];
    const float* b_ih_b = (const float*)d_in[9];
    const float* b_hh_b = (const float*)d_in[10];

    float* out = (float*)d_out;
    float* h_n = out + (size_t)SEQ * BATCH * 2 * H;
    float* c_n = h_n + (size_t)2 * BATCH * H;

    dim3 grid(BATCH / 2, 2), block(64);
    hipLaunchKernelGGL(lstm_bidir, grid, block, 0, stream,
                       x, h0, c0, w_ih_f, w_hh_f, b_ih_f, b_hh_f,
                       w_ih_b, w_hh_b, b_ih_b, b_hh_b, out, h_n, c_n);
}